// Round 5
// baseline (301.360 us; speedup 1.0000x reference)
//
#include <hip/hip_runtime.h>
#include <hip/hip_bf16.h>
#include <stdint.h>

// ReadoutLayer: Wx = x @ W^T (+b cancels under BN), BatchNorm(train) over B*T,
// then ut = a*ut + (1-a)*wxn per t with acc += softmax(ut, axis=H).
// R9 == R7/R8 with one defensive change: explicit 3rd __syncthreads() in
// soft_k's chunk loop (the two-barrier rotation was the only correctness-by-
// argument construct; now correctness-by-structure, cost ~5 barriers/block).
// Two container failures of identical source: full hazard audit (bounds,
// barrier uniformity, graph-capture legality, idempotent re-launch) found no
// defect; all other code is HW-verified R6 structure or audited arithmetic.
// R7 rationale: tail was 210/301 us (R6: top-5 all gemm at 90 us). Fixes:
//  - kL 20->16; chunk-EWMA fused into gemm epilogue as geometric-weight dot
//    product over acc regs (+shfl_xor(32)) -> agg_raw_k + 65.5 MB re-read GONE.
//  - finalize+scan fused (grid 32, redundant BN-param compute per block).
//  - out_red fused into soft_k via 25-deep atomicAdd on zeroed out.
//  - soft_k 3200->800 blocks (5 chunks each), u carried across chunks.
// Dispatches 9 -> 7; Wxb passes write+2reads -> write+1read.

namespace {
constexpr int kB = 32;
constexpr int kT = 2000;
constexpr int kD = 512;
constexpr int kH = 512;
constexpr int kM = kB * kT;   // 64000 rows
constexpr int kBM = 128;      // rows per gemm block
constexpr int kNB = kM / kBM; // 500 blocks
constexpr int kL = 16;        // chunk length (divides kT and kBM)
constexpr int kC = kT / kL;   // 125 chunks per batch
constexpr int kG = 5;         // chunks per soft_k block
constexpr int kNG = kC / kG;  // 25 groups per batch
constexpr float kALo = 0.81873075307798182f;  // exp(-1/5)
constexpr float kAHi = 0.96078943915232320f;  // exp(-1/25)

typedef __bf16 bf16x8 __attribute__((ext_vector_type(8)));
typedef float floatx16 __attribute__((ext_vector_type(16)));

__device__ __forceinline__ float bf2f(unsigned short u) {
  return __builtin_bit_cast(float, (unsigned)u << 16);
}
__device__ __forceinline__ float clipa(float a) {
  return fminf(fmaxf(a, kALo), kAHi);
}
__device__ __forceinline__ float pow16(float a) {
  const float a2 = a * a, a4 = a2 * a2, a8 = a4 * a4;
  return a8 * a8;
}
// async global->LDS, 16B per lane; LDS dest = wave-uniform base + lane*16
__device__ __forceinline__ void gld_lds16(const void* g, void* l) {
  __builtin_amdgcn_global_load_lds(
      (const __attribute__((address_space(1))) uint32_t*)g,
      (__attribute__((address_space(3))) uint32_t*)(uintptr_t)l, 16, 0, 0);
}

// ---------- K0: W f32 -> bf16, permuted to Wbf2[k8][h][8] (k8 = k/8) ----------
__global__ __launch_bounds__(256) void wcvt_k(const float* __restrict__ W,
                                              __bf16* __restrict__ Wbf) {
  const int t = blockIdx.x * 256 + threadIdx.x;  // t = h*64 + k8
  const float4 a0 = ((const float4*)W)[t * 2];
  const float4 a1 = ((const float4*)W)[t * 2 + 1];
  bf16x8 v;
  v[0] = (__bf16)a0.x; v[1] = (__bf16)a0.y; v[2] = (__bf16)a0.z; v[3] = (__bf16)a0.w;
  v[4] = (__bf16)a1.x; v[5] = (__bf16)a1.y; v[6] = (__bf16)a1.z; v[7] = (__bf16)a1.w;
  const int h = t >> 6, k8 = t & 63;
  *(bf16x8*)(Wbf + ((size_t)k8 * 512 + h) * 8) = v;  // scattered 16B: one-time
}

// ---------- K1: GEMM 128x512 per block + stats + fused chunk-EWMA ----------
// 512 threads = 8 waves; wave w: col-tiles ct0=w*2..+2, row-tiles rt=0..3.
__global__ __launch_bounds__(512, 2) void gemm_k(const float* __restrict__ X,
                                                 const __bf16* __restrict__ Wbf,
                                                 const float* __restrict__ alpha,
                                                 unsigned short* __restrict__ Wxb,
                                                 float* __restrict__ vbuf,
                                                 float* __restrict__ partial) {
  __shared__ alignas(16) __bf16 As2[2][4][128][8];  // [buf][kq][row][k%8], 2x8KB
  __shared__ alignas(16) bf16x8 Bs2[2][2048];       // [buf][kq*512+col], 2x32KB
  __shared__ float sred[2][kH];
  const int tid = threadIdx.x;
  const size_t row0 = (size_t)blockIdx.x * kBM;
  const int w = tid >> 6, L = tid & 63;
  const int ct0 = w * 2;
  const int lhalf = L >> 5, l32 = L & 31;
  const int arow = tid >> 2, akq = tid & 3;  // A staging: 8 f32 -> 1 bf16x8/thread

  floatx16 acc[4][2] = {};
  const float* xptr = X + (row0 + arow) * kD + akq * 8;

  // ---- prologue: stage slab 0 into buf 0, prefetch A regs for slab 1 ----
  float4 a0 = *(const float4*)xptr;
  float4 a1 = *(const float4*)(xptr + 4);
#pragma unroll
  for (int j = 0; j < 4; ++j) {
    const int ci = j * 512 + tid;
    gld_lds16(Wbf + (size_t)ci * 8, (char*)&Bs2[0][0] + (size_t)ci * 16);
  }
  {
    bf16x8 av;
    av[0] = (__bf16)a0.x; av[1] = (__bf16)a0.y; av[2] = (__bf16)a0.z; av[3] = (__bf16)a0.w;
    av[4] = (__bf16)a1.x; av[5] = (__bf16)a1.y; av[6] = (__bf16)a1.z; av[7] = (__bf16)a1.w;
    *(bf16x8*)&As2[0][akq][arow][0] = av;
  }
  a0 = *(const float4*)(xptr + 32);
  a1 = *(const float4*)(xptr + 36);
  asm volatile("s_waitcnt vmcnt(2) lgkmcnt(0)" ::: "memory");
  __builtin_amdgcn_s_barrier();

#pragma unroll 1
  for (int s = 0; s < 16; ++s) {
    const int buf = s & 1;
    if (s < 15) {
      // issue B(s+1) into buf^1 (stays in flight across MFMA phase)
#pragma unroll
      for (int j = 0; j < 4; ++j) {
        const int ci = j * 512 + tid;
        gld_lds16(Wbf + ((size_t)(s + 1) * 2048 + ci) * 8,
                  (char*)&Bs2[buf ^ 1][0] + (size_t)ci * 16);
      }
      // A(s+1) regs -> bf16 -> LDS
      bf16x8 av;
      av[0] = (__bf16)a0.x; av[1] = (__bf16)a0.y; av[2] = (__bf16)a0.z; av[3] = (__bf16)a0.w;
      av[4] = (__bf16)a1.x; av[5] = (__bf16)a1.y; av[6] = (__bf16)a1.z; av[7] = (__bf16)a1.w;
      *(bf16x8*)&As2[buf ^ 1][akq][arow][0] = av;
      if (s < 14) {  // X prefetch for slab s+2 rides through the barrier
        a0 = *(const float4*)(xptr + (s + 2) * 32);
        a1 = *(const float4*)(xptr + (s + 2) * 32 + 4);
      }
    }
    // ---- compute slab s from buf ----
#pragma unroll
    for (int kh = 0; kh < 2; ++kh) {
      const int kq = kh * 2 + lhalf;
      const bf16x8 af0 = *(const bf16x8*)&As2[buf][kq][l32][0];
      const bf16x8 af1 = *(const bf16x8*)&As2[buf][kq][32 + l32][0];
      const bf16x8 af2 = *(const bf16x8*)&As2[buf][kq][64 + l32][0];
      const bf16x8 af3 = *(const bf16x8*)&As2[buf][kq][96 + l32][0];
      const bf16x8 b0 = Bs2[buf][kq * 512 + ct0 * 32 + l32];
      const bf16x8 b1 = Bs2[buf][kq * 512 + (ct0 + 1) * 32 + l32];
      acc[0][0] = __builtin_amdgcn_mfma_f32_32x32x16_bf16(af0, b0, acc[0][0], 0, 0, 0);
      acc[0][1] = __builtin_amdgcn_mfma_f32_32x32x16_bf16(af0, b1, acc[0][1], 0, 0, 0);
      acc[1][0] = __builtin_amdgcn_mfma_f32_32x32x16_bf16(af1, b0, acc[1][0], 0, 0, 0);
      acc[1][1] = __builtin_amdgcn_mfma_f32_32x32x16_bf16(af1, b1, acc[1][1], 0, 0, 0);
      acc[2][0] = __builtin_amdgcn_mfma_f32_32x32x16_bf16(af2, b0, acc[2][0], 0, 0, 0);
      acc[2][1] = __builtin_amdgcn_mfma_f32_32x32x16_bf16(af2, b1, acc[2][1], 0, 0, 0);
      acc[3][0] = __builtin_amdgcn_mfma_f32_32x32x16_bf16(af3, b0, acc[3][0], 0, 0, 0);
      acc[3][1] = __builtin_amdgcn_mfma_f32_32x32x16_bf16(af3, b1, acc[3][1], 0, 0, 0);
    }
    if (s < 15) {
      if (s < 14)
        asm volatile("s_waitcnt vmcnt(2) lgkmcnt(0)" ::: "memory");
      else
        asm volatile("s_waitcnt vmcnt(0) lgkmcnt(0)" ::: "memory");
      __builtin_amdgcn_s_barrier();
    }
  }

  // ---- epilogue 1: column sums/sumsq -> LDS -> plain partial stores ----
  __syncthreads();
  sred[0][tid] = 0.f;
  sred[1][tid] = 0.f;
  __syncthreads();
#pragma unroll
  for (int c = 0; c < 2; ++c) {
    float s = 0.f, q = 0.f;
#pragma unroll
    for (int rt = 0; rt < 4; ++rt) {
#pragma unroll
      for (int r = 0; r < 16; ++r) {
        const float v = acc[rt][c][r];
        s += v;
        q += v * v;
      }
    }
    s += __shfl_xor(s, 32);
    q += __shfl_xor(q, 32);
    if (lhalf == 0) {
      atomicAdd(&sred[0][(ct0 + c) * 32 + l32], s);  // LDS atomics only
      atomicAdd(&sred[1][(ct0 + c) * 32 + l32], q);
    }
  }

  // ---- epilogue 1.5: fused raw chunk-EWMA (kL=16 rows per chunk) ----
  // EWMA over a fixed window = dot product with geometric weights:
  //   v = sum_i a^(15-i) (1-a) wx_i.
  // C/D layout: row = 4*lhalf + (r&3) + 8*(r>>2); chunk c32 covers regs
  // r = c32*8 + j. Row-in-chunk i = (j&3) + 8*(j>>2) + 4*lhalf, so the
  // exponent set is {11,10,9,8,3,2,1,0} for lhalf=1 and that +4 for lhalf=0.
#pragma unroll
  for (int c = 0; c < 2; ++c) {
    const int col = (ct0 + c) * 32 + l32;
    const float a = clipa(alpha[col]);
    const float oma = 1.0f - a;
    const float a2 = a * a, a4 = a2 * a2, a8 = a4 * a4;
    float wgt[8];
    wgt[0] = a8 * a2 * a; wgt[1] = a8 * a2; wgt[2] = a8 * a; wgt[3] = a8;
    wgt[4] = a2 * a;      wgt[5] = a2;      wgt[6] = a;      wgt[7] = 1.0f;
    const float mult = (lhalf == 0) ? a4 * oma : oma;
#pragma unroll
    for (int j = 0; j < 8; ++j) wgt[j] *= mult;
#pragma unroll
    for (int rt = 0; rt < 4; ++rt) {
#pragma unroll
      for (int c32 = 0; c32 < 2; ++c32) {
        float S = 0.f;
#pragma unroll
        for (int j = 0; j < 8; ++j) S += wgt[j] * acc[rt][c][c32 * 8 + j];
        S += __shfl_xor(S, 32);
        if (lhalf == 0) {
          const int g = (int)(row0 >> 4) + rt * 2 + c32;  // global chunk id
          vbuf[(size_t)g * kH + col] = S;
        }
      }
    }
  }

  // ---- epilogue 2: store Wx bf16, packed dword pairs via shfl ----
#pragma unroll
  for (int rt = 0; rt < 4; ++rt) {
#pragma unroll
    for (int c = 0; c < 2; ++c) {
      const int col = (ct0 + c) * 32 + l32;
#pragma unroll
      for (int r = 0; r < 16; ++r) {
        const int row = rt * 32 + 4 * lhalf + (r & 3) + 8 * (r >> 2);
        const unsigned short u = __builtin_bit_cast(unsigned short, (__bf16)acc[rt][c][r]);
        const unsigned un = __shfl_down((unsigned)u, 1);
        if ((l32 & 1) == 0)
          *(unsigned*)(Wxb + (row0 + row) * (size_t)kH + col) = (unsigned)u | (un << 16);
      }
    }
  }
  __syncthreads();
  partial[(size_t)blockIdx.x * 1024 + tid] = sred[0][tid];
  partial[(size_t)blockIdx.x * 1024 + 512 + tid] = sred[1][tid];
}

// ---------- K2: reduce per-block partials (25 blocks x 20 rows = 500) ----------
__global__ __launch_bounds__(512) void red1_k(const float* __restrict__ partial,
                                              float* __restrict__ sums) {
  const int tid = threadIdx.x;
  const int r0 = blockIdx.x * 20;
  float s0 = 0.f, s1 = 0.f;
#pragma unroll 5
  for (int r = 0; r < 20; ++r) {
    s0 += partial[(size_t)(r0 + r) * 1024 + tid];
    s1 += partial[(size_t)(r0 + r) * 1024 + 512 + tid];
  }
  atomicAdd(&sums[tid], s0);        // 25-deep contention: negligible
  atomicAdd(&sums[kH + tid], s1);
}

// ---------- K3: finalize BN params + chunk-boundary scan (fused) ----------
// grid = 32 (one block per batch); BN params computed redundantly per block.
// prm: [0]=scale [512]=shift [1024]=a [1536]=1-a  (written by block 0)
// u' = a^16 u + sc*v + sh*(1-a^16); group-start u written to ustart.
__global__ __launch_bounds__(512) void fin_scan_k(const float* __restrict__ sums,
                                                  const float* __restrict__ alpha,
                                                  const float* __restrict__ gamma,
                                                  const float* __restrict__ beta,
                                                  const float* __restrict__ ut0,
                                                  float* __restrict__ prm,
                                                  const float* __restrict__ vbuf,
                                                  float* __restrict__ ustart) {
  const int h = threadIdx.x;
  const int b = blockIdx.x;
  const float inv_n = 1.0f / (float)kM;
  const float mean = sums[h] * inv_n;
  const float var = sums[kH + h] * inv_n - mean * mean;
  const float sc = gamma[h] * rsqrtf(var + 1e-5f);
  const float sh = beta[h] - mean * sc;
  const float a = clipa(alpha[h]);
  if (b == 0) {
    prm[h] = sc;
    prm[kH + h] = sh;
    prm[2 * kH + h] = a;
    prm[3 * kH + h] = 1.0f - a;
  }
  const float a16 = pow16(a);
  const float shc = sh * (1.0f - a16);
  float u = ut0[(size_t)b * kH + h];
  float vc[kG];
#pragma unroll 1
  for (int cb = 0; cb < kC; cb += kG) {
#pragma unroll
    for (int j = 0; j < kG; ++j)
      vc[j] = vbuf[((size_t)b * kC + cb + j) * kH + h];  // independent, pipelined
    ustart[((size_t)b * kNG + cb / kG) * kH + h] = u;    // group-start u
#pragma unroll
    for (int j = 0; j < kG; ++j) u = a16 * u + sc * vc[j] + shc;
  }
}

// ---------- K4: softmax accumulation over 5 chunks + atomic out ----------
__global__ __launch_bounds__(512) void soft_k(const unsigned short* __restrict__ Wxb,
                                              const float* __restrict__ prm,
                                              const float* __restrict__ ustart,
                                              float* __restrict__ out) {
  __shared__ float part[kL][9];
  __shared__ float zinv[kL];
  const int bc = blockIdx.x;               // 0..799
  const int b = bc / kNG, grp = bc % kNG;
  const int h = threadIdx.x;
  const int wv = h >> 6, lane = h & 63;
  const float sc = prm[h], sh = prm[kH + h];
  const float a = prm[2 * kH + h], oma = prm[3 * kH + h];
  float u = ustart[(size_t)bc * kH + h];
  const unsigned short* base =
      Wxb + ((size_t)b * kT + (size_t)grp * kG * kL) * kH + h;
  float acc = 0.f;
#pragma unroll 1
  for (int cc = 0; cc < kG; ++cc) {
    float e[kL];
#pragma unroll
    for (int i = 0; i < kL; ++i) {
      const float wvx = bf2f(base[(size_t)(cc * kL + i) * kH]) * sc + sh;
      u = a * u + oma * wvx;
      e[i] = __expf(u);  // |u| <~ 2 after BN+EWMA damping: no max-subtract needed
    }
#pragma unroll
    for (int i = 0; i < kL; ++i) {
      float s = e[i];
#pragma unroll
      for (int off = 32; off > 0; off >>= 1) s += __shfl_xor(s, off);
      if (lane == 0) part[i][wv] = s;
    }
    __syncthreads();
    if (h < kL) {
      float s = 0.f;
#pragma unroll
      for (int j = 0; j < 8; ++j) s += part[h][j];
      zinv[h] = 1.0f / s;
    }
    __syncthreads();
#pragma unroll
    for (int i = 0; i < kL; ++i) acc += e[i] * zinv[i];
    __syncthreads();  // defensive: make iteration rotation trivially race-free
  }
  atomicAdd(&out[(size_t)b * kH + h], acc);  // 25-deep per address
}

}  // namespace

extern "C" void kernel_launch(void* const* d_in, const int* in_sizes, int n_in,
                              void* d_out, int out_size, void* d_ws, size_t ws_size,
                              hipStream_t stream) {
  const float* x = (const float*)d_in[0];      // [32,2000,512]
  const float* Wm = (const float*)d_in[1];     // [512,512]
  // d_in[2] = b: unused — BN mean subtraction cancels the bias exactly
  const float* alpha = (const float*)d_in[3];
  const float* gamma = (const float*)d_in[4];
  const float* beta = (const float*)d_in[5];
  const float* ut0 = (const float*)d_in[6];
  float* out = (float*)d_out;                  // [32,1,512]

  float* wsp = (float*)d_ws;
  float* vbuf = wsp;                                   // 32*125*512 = 2,048,000 f
  float* ustart = vbuf + (size_t)kB * kC * kH;         // 32*25*512 = 409,600 f
  float* partial = ustart + (size_t)kB * kNG * kH;     // 500*1024 f
  float* sums = partial + (size_t)500 * 1024;          // 1024 f
  float* prm = sums + 2 * kH;                          // 2048 f
  __bf16* Wbf = (__bf16*)(prm + 4 * kH);               // 262144 bf16 (16B-aligned)
  unsigned short* Wxb = (unsigned short*)(Wbf + (size_t)kH * kD);  // 65.5 MB

  hipMemsetAsync(sums, 0, 2 * kH * sizeof(float), stream);
  hipMemsetAsync(out, 0, (size_t)kB * kH * sizeof(float), stream);
  wcvt_k<<<128, 256, 0, stream>>>(Wm, Wbf);
  gemm_k<<<kNB, 512, 0, stream>>>(x, Wbf, alpha, Wxb, vbuf, partial);
  red1_k<<<25, 512, 0, stream>>>(partial, sums);
  fin_scan_k<<<kB, 512, 0, stream>>>(sums, alpha, gamma, beta, ut0, prm, vbuf, ustart);
  soft_k<<<kB * kNG, 512, 0, stream>>>(Wxb, prm, ustart, out);
}